// Round 1
// baseline (360.401 us; speedup 1.0000x reference)
//
#include <hip/hip_runtime.h>

// MaxUnpooling2D as a GATHER over the output (no memset, single kernel).
// B=16, H=W=64, C=256, OH=OW=128, 2x2 windows.
//
// Key invariant (max_pool_with_argmax semantics): mask[b,h,w,c] is a flat
// index into [OH,OW,C] that lies INSIDE window (h,w). Therefore every output
// element (b,oh,ow,c) belongs to exactly one window (oh/2, ow/2) and equals
//   (mask[b,oh/2,ow/2,c] == flat(oh,ow,c)) ? updates[b,oh/2,ow/2,c] : 0
// One thread owns one (b,h,w,c0..c0+3) quad and writes all 4 window positions
// -> output written exactly once, inputs read exactly once:
//    traffic = 64 MiB (updates) + 64 MiB (mask) + 256 MiB (out) = 384 MiB.

constexpr int B = 16;
constexpr int H = 64, W = 64, C = 256;
constexpr int OH = 2 * H, OW = 2 * W;
constexpr long long OUT_PER_BATCH = (long long)OH * OW * C;  // 4,194,304
constexpr int N_THREADS = B * H * W * (C / 4);               // 4,194,304

typedef float f32x4 __attribute__((ext_vector_type(4)));
typedef int   i32x4 __attribute__((ext_vector_type(4)));

__global__ __launch_bounds__(256) void unpool_gather_kernel(
    const f32x4* __restrict__ upd4,
    const i32x4* __restrict__ mask4,
    float* __restrict__ out) {
    int i = blockIdx.x * blockDim.x + threadIdx.x;
    if (i >= N_THREADS) return;

    // i is the flat quad index in [B,H,W,C/4] order (matches input layout).
    int c0 = (i & 63) << 2;      // channel of first element in the quad
    int w  = (i >> 6) & 63;
    int h  = (i >> 12) & 63;
    int b  = i >> 18;

    i32x4 m = mask4[i];          // per-batch flat indices for c0..c0+3
    f32x4 u = upd4[i];

    float* obase = out + (long long)b * OUT_PER_BATCH;
    int oh = h << 1, ow = w << 1;

#pragma unroll
    for (int dy = 0; dy < 2; ++dy) {
#pragma unroll
        for (int dx = 0; dx < 2; ++dx) {
            int flat = ((oh + dy) * OW + (ow + dx)) * C + c0;
            f32x4 r;
            r.x = (m.x == flat)     ? u.x : 0.0f;
            r.y = (m.y == flat + 1) ? u.y : 0.0f;
            r.z = (m.z == flat + 2) ? u.z : 0.0f;
            r.w = (m.w == flat + 3) ? u.w : 0.0f;
            // write-once data: nontemporal store, don't pollute L2/L3
            __builtin_nontemporal_store(r, (f32x4*)(obase + flat));
        }
    }
}

extern "C" void kernel_launch(void* const* d_in, const int* in_sizes, int n_in,
                              void* d_out, int out_size, void* d_ws, size_t ws_size,
                              hipStream_t stream) {
    const f32x4* upd4  = (const f32x4*)d_in[0];
    const i32x4* mask4 = (const i32x4*)d_in[1];
    float*       out   = (float*)d_out;

    // No memset: the kernel writes every output element exactly once.
    const int block = 256;
    const int grid  = N_THREADS / block;  // 16384 blocks, exact
    unpool_gather_kernel<<<grid, block, 0, stream>>>(upd4, mask4, out);
}

// Round 2
// 357.960 us; speedup vs baseline: 1.0068x; 1.0068x over previous
//
#include <hip/hip_runtime.h>

// MaxUnpooling2D as a GATHER over the output (no memset, single kernel).
// B=16, H=W=64, C=256, OH=OW=128, 2x2 windows.
//
// Key invariant (max_pool_with_argmax semantics): mask[b,h,w,c] is a flat
// index into [OH,OW,C] that lies INSIDE window (h,w). Therefore every output
// element (b,oh,ow,c) belongs to exactly one window (oh/2, ow/2) and equals
//   (mask[b,oh/2,ow/2,c] == flat(oh,ow,c)) ? updates[b,oh/2,ow/2,c] : 0
// One thread owns one (b,h,w,c0..c0+3) quad and writes all 4 window positions
// -> output written exactly once, inputs read exactly once:
//    traffic = 64 MiB (updates) + 64 MiB (mask) + 256 MiB (out) = 384 MiB.
//
// R1 lesson: __builtin_nontemporal_store regressed the store path ~3x
// (nt = no-allocate/streaming policy defeats L2 write-combining for 16 B
// per-lane stores; harness's own plain-store fills sustain 6.5 TB/s).
// Plain stores through L2: a wave's 4 stores are each 1 KiB contiguous,
// full 128 B lines -> no write-allocate reads.

constexpr int B = 16;
constexpr int H = 64, W = 64, C = 256;
constexpr int OH = 2 * H, OW = 2 * W;
constexpr long long OUT_PER_BATCH = (long long)OH * OW * C;  // 4,194,304
constexpr int N_THREADS = B * H * W * (C / 4);               // 4,194,304

typedef float f32x4 __attribute__((ext_vector_type(4)));
typedef int   i32x4 __attribute__((ext_vector_type(4)));

__global__ __launch_bounds__(256) void unpool_gather_kernel(
    const f32x4* __restrict__ upd4,
    const i32x4* __restrict__ mask4,
    float* __restrict__ out) {
    int i = blockIdx.x * blockDim.x + threadIdx.x;
    if (i >= N_THREADS) return;

    // i is the flat quad index in [B,H,W,C/4] order (matches input layout).
    int c0 = (i & 63) << 2;      // channel of first element in the quad
    int w  = (i >> 6) & 63;
    int h  = (i >> 12) & 63;
    int b  = i >> 18;

    i32x4 m = mask4[i];          // per-batch flat indices for c0..c0+3
    f32x4 u = upd4[i];

    float* obase = out + (long long)b * OUT_PER_BATCH;
    int oh = h << 1, ow = w << 1;

#pragma unroll
    for (int dy = 0; dy < 2; ++dy) {
#pragma unroll
        for (int dx = 0; dx < 2; ++dx) {
            int flat = ((oh + dy) * OW + (ow + dx)) * C + c0;
            f32x4 r;
            r.x = (m.x == flat)     ? u.x : 0.0f;
            r.y = (m.y == flat + 1) ? u.y : 0.0f;
            r.z = (m.z == flat + 2) ? u.z : 0.0f;
            r.w = (m.w == flat + 3) ? u.w : 0.0f;
            *(f32x4*)(obase + flat) = r;   // plain store, L2 write-combined
        }
    }
}

extern "C" void kernel_launch(void* const* d_in, const int* in_sizes, int n_in,
                              void* d_out, int out_size, void* d_ws, size_t ws_size,
                              hipStream_t stream) {
    const f32x4* upd4  = (const f32x4*)d_in[0];
    const i32x4* mask4 = (const i32x4*)d_in[1];
    float*       out   = (float*)d_out;

    // No memset: the kernel writes every output element exactly once.
    const int block = 256;
    const int grid  = N_THREADS / block;  // 16384 blocks, exact
    unpool_gather_kernel<<<grid, block, 0, stream>>>(upd4, mask4, out);
}